// Round 6
// baseline (1630.096 us; speedup 1.0000x reference)
//
#include <hip/hip_runtime.h>
#include <stdint.h>

// FastRNN: B=64, T=512, I=256, H=512, fp32.
//   K1: wx = x @ W + bias  (bf16 MFMA GEMM) — unchanged.
//   K2: h_t = sb*h + sa*tanh(wx_t + h @ U).
// R12: R10's tiling (8 blocks = 4 batch-groups x 2 j-slices, 512 thr,
//   own half of h-state LDS-resident, ONE 8KB partner half on the global
//   path) rebuilt on R6's PROVEN protocol primitives, after R10/R11's
//   hand-rolled async path failed twice unexplained:
//   - poll: __hip_atomic_load(relaxed, agent) batch check-reload loop
//     (R6's exact idiom; no inline-asm split load/waitcnt),
//   - early-issue at loop tail into plain vars (R8's proven-safe half;
//     compiler inserts the waits),
//   - publish: barrier F restored, then __hip_atomic_store u64 pairs
//     (publish read of LDS is barrier-ordered; no wave-privacy reliance).
//   Two __syncthreads per step, like R6.

#define B_ 64
#define T_ 512
#define I_ 256
#define H_ 512
#define M_ (B_ * T_)  // 32768

#define WXB_BYTES  ((size_t)M_ * H_ * 4)       // 64 MiB fp32
#define HHALF_BYTES ((size_t)B_ * H_ * 2)      // 64 KiB bf16 per parity

typedef short v8s __attribute__((ext_vector_type(8)));
typedef float v4f __attribute__((ext_vector_type(4)));
typedef unsigned long long u64t;

__device__ __forceinline__ uint16_t f2bf(float x) {
    union { float f; uint32_t u; } v; v.f = x;
    return (uint16_t)((v.u + 0x7FFFu + ((v.u >> 16) & 1u)) >> 16);
}

// --------------- K1: wxb[m][j] = x[m][:] @ W[:][j] + bias[j] ----------------
__global__ __launch_bounds__(256) void wx_gemm(
        const float* __restrict__ x, const float* __restrict__ W,
        const float* __restrict__ bias, float* __restrict__ wxb) {
    __shared__ uint16_t Asl[64][40];
    __shared__ uint16_t Bsl[4 * 64 * 8];

    const int tid = threadIdx.x;
    const int lane = tid & 63;
    const int w = tid >> 6;
    const int q = lane >> 4, c = lane & 15;
    const int mbase = (int)(blockIdx.x >> 3) * 64;
    const int nbase = (int)(blockIdx.x & 7) * 64;

    v4f acc[4];
    #pragma unroll
    for (int i = 0; i < 4; ++i) acc[i] = (v4f){0.f, 0.f, 0.f, 0.f};

    for (int ks = 0; ks < I_; ks += 32) {
        {
            int row = tid >> 2, c4 = tid & 3;
            const float* gp = x + (size_t)(mbase + row) * I_ + ks + c4 * 8;
            float4 f0 = *(const float4*)gp;
            float4 f1 = *(const float4*)(gp + 4);
            uint16_t* dp = &Asl[row][c4 * 8];
            dp[0] = f2bf(f0.x); dp[1] = f2bf(f0.y); dp[2] = f2bf(f0.z); dp[3] = f2bf(f0.w);
            dp[4] = f2bf(f1.x); dp[5] = f2bf(f1.y); dp[6] = f2bf(f1.z); dp[7] = f2bf(f1.w);
        }
        {
            int nt = tid >> 6;
            const float* gp = W + (size_t)(ks + q * 8) * H_ + nbase + nt * 16 + c;
            union { v8s v; uint16_t u[8]; } pk;
            #pragma unroll
            for (int jj = 0; jj < 8; ++jj) pk.u[jj] = f2bf(gp[(size_t)jj * H_]);
            *(v8s*)&Bsl[(nt * 64 + lane) * 8] = pk.v;
        }
        __syncthreads();
        const v8s* Bf = (const v8s*)Bsl;
        v8s a = *(const v8s*)&Asl[w * 16 + c][q * 8];
        #pragma unroll
        for (int nt = 0; nt < 4; ++nt) {
            v8s b = Bf[nt * 64 + lane];
            acc[nt] = __builtin_amdgcn_mfma_f32_16x16x32_bf16(a, b, acc[nt], 0, 0, 0);
        }
        __syncthreads();
    }
    #pragma unroll
    for (int nt = 0; nt < 4; ++nt) {
        int j = nbase + nt * 16 + c;
        float bj = bias[j];
        #pragma unroll
        for (int r = 0; r < 4; ++r) {
            int m = mbase + w * 16 + q * 4 + r;
            wxb[(size_t)m * H_ + j] = acc[nt][r] + bj;
        }
    }
}

// --------------- K2: recurrent scan ----------------------------------------
__global__ __launch_bounds__(512, 2) void rnn_scan(
        const float* __restrict__ U, const float* __restrict__ wxb,
        const float* __restrict__ alpha, const float* __restrict__ beta,
        float* __restrict__ out, uint16_t* __restrict__ Hbuf) {
    __shared__ __align__(16) uint16_t Als[2][16][520];  // dbuf full-H state, +8 pad

    const int bid = blockIdx.x;       // 0..7
    const int g = bid >> 1, s = bid & 1;
    const int tid = threadIdx.x;      // 0..511
    const int lane = tid & 63;
    const int w = tid >> 6;           // wave 0..7
    const int q = lane >> 4, c = lane & 15;

    float sa, sb;
    { float a = alpha[0], b = beta[0];
      sa = 1.f / (1.f + __expf(-a)); sb = 1.f / (1.f + __expf(-b)); }

    // Loop-invariant U B-frags: wave w owns ntiles 2w, 2w+1 of our 256-col slice.
    v8s Uf[2][16];
    #pragma unroll
    for (int nt = 0; nt < 2; ++nt) {
        int jg = s * 256 + (2 * w + nt) * 16 + c;
        #pragma unroll
        for (int kt = 0; kt < 16; ++kt) {
            const float* gp = U + (size_t)(kt * 32 + q * 8) * H_ + jg;
            union { v8s v; uint16_t u[8]; } pk;
            #pragma unroll
            for (int jj = 0; jj < 8; ++jj) pk.u[jj] = f2bf(gp[(size_t)jj * H_]);
            Uf[nt][kt] = pk.v;
        }
    }
    float hold[2][4];
    #pragma unroll
    for (int nt = 0; nt < 2; ++nt)
        #pragma unroll
        for (int r = 0; r < 4; ++r) hold[nt][r] = 0.f;

    // wx prefetch: one step ahead.
    float wxv[2][4], wxn[2][4];
    #pragma unroll
    for (int nt = 0; nt < 2; ++nt) {
        int jg = s * 256 + (2 * w + nt) * 16 + c;
        #pragma unroll
        for (int r = 0; r < 4; ++r) {
            int bg = g * 16 + q * 4 + r;
            wxn[nt][r] = __builtin_nontemporal_load(
                &wxb[((size_t)bg * T_ + 0) * H_ + jg]);
        }
    }

    // Partner poll mapping: partner half = 16 rows x 256 cols = 8KB; thread
    // owns one 16B chunk: row tid>>5, cols (1-s)*256 + (tid&31)*8 .. +7.
    // A wave's chunk addresses are lane-contiguous (1KB runs).
    const int prow = tid >> 5;
    const int pcol = (1 - s) * 256 + (tid & 31) * 8;                // u16
    const size_t poff = ((size_t)(g * 16 + prow)) * H_ + pcol;      // u16
    // Publish mapping: thread publishes row lane>>2, cols s*256 + w*32 +
    // (lane&3)*8 of the block's own slice (read from LDS after barrier F).
    const int orow = lane >> 2;
    const int ocol = s * 256 + w * 32 + (lane & 3) * 8;             // u16
    const size_t ooff = ((size_t)(g * 16 + orow)) * H_ + ocol;      // u16

    u64t e0 = 0, e1 = 0;   // early-issued partner poll loads (R8 idiom)

    for (int t = 0; t < T_; ++t) {
        const int p = t & 1;
        // rotate wx prefetch buffer
        #pragma unroll
        for (int nt = 0; nt < 2; ++nt)
            #pragma unroll
            for (int r = 0; r < 4; ++r) wxv[nt][r] = wxn[nt][r];

        // ---- poll partner half into Als[p] (own half was written by last
        //      step's epilogue); R6-proven atomic check-reload loop ----
        if (t == 0) {
            u64t z = 0;
            #pragma unroll
            for (int u2 = 0; u2 < 4; ++u2) {
                int k2 = tid * 4 + u2;               // 2048 u64s = 16r x 512c
                *((u64t*)&Als[0][k2 >> 7][0] + (k2 & 127)) = z;
            }
        } else {
            const u64t* gp = (const u64t*)(Hbuf + (size_t)p * (B_ * H_) + poff);
            const uint32_t tau = (uint32_t)((t >> 1) & 1);
            const u64t lsb = 0x0001000100010001ull;
            const u64t want = tau ? lsb : 0ull;
            u64t v0 = e0, v1 = e1;
            for (int guard = 0; guard < (1 << 20); ++guard) {
                u64t x = ((v0 ^ want) | (v1 ^ want)) & lsb;
                if (!x) break;
                v0 = __hip_atomic_load(&gp[0], __ATOMIC_RELAXED,
                                       __HIP_MEMORY_SCOPE_AGENT);
                v1 = __hip_atomic_load(&gp[1], __ATOMIC_RELAXED,
                                       __HIP_MEMORY_SCOPE_AGENT);
            }
            u64t* dp = (u64t*)&Als[p][prow][pcol];
            dp[0] = v0; dp[1] = v1;
        }
        __syncthreads();  // C: Als[p] complete
        // ---- prefetch wx for t+1 (off the critical chain) ----
        if (t + 1 < T_) {
            #pragma unroll
            for (int nt = 0; nt < 2; ++nt) {
                int jg = s * 256 + (2 * w + nt) * 16 + c;
                #pragma unroll
                for (int r = 0; r < 4; ++r) {
                    int bg = g * 16 + q * 4 + r;
                    wxn[nt][r] = __builtin_nontemporal_load(
                        &wxb[((size_t)bg * T_ + (t + 1)) * H_ + jg]);
                }
            }
        }
        // ---- P = H @ U_slice ----
        v4f acc0 = (v4f){0.f, 0.f, 0.f, 0.f};
        v4f acc1 = (v4f){0.f, 0.f, 0.f, 0.f};
        #pragma unroll
        for (int kt = 0; kt < 16; ++kt) {
            v8s a = *(const v8s*)((const uint16_t*)&Als[p][c][0] + kt * 32 + q * 8);
            acc0 = __builtin_amdgcn_mfma_f32_16x16x32_bf16(a, Uf[0][kt], acc0, 0, 0, 0);
            acc1 = __builtin_amdgcn_mfma_f32_16x16x32_bf16(a, Uf[1][kt], acc1, 0, 0, 0);
        }
        // ---- epilogue: fp32 state in regs; tagged bf16 -> Als[1-p] own
        //      region (this IS next step's A-staging for our half) ----
        const uint16_t tauw = (uint16_t)(((t + 1) >> 1) & 1);
        #pragma unroll
        for (int nt = 0; nt < 2; ++nt) {
            v4f av = nt ? acc1 : acc0;
            int jl = s * 256 + (2 * w + nt) * 16 + c;
            #pragma unroll
            for (int r = 0; r < 4; ++r) {
                float pre = av[r] + wxv[nt][r];
                float ex = __expf(pre + pre);                           // e^{2x}
                float ct = 1.f - 2.f * __builtin_amdgcn_rcpf(ex + 1.f); // tanh
                float hn = sb * hold[nt][r] + sa * ct;
                hold[nt][r] = hn;
                Als[1 - p][q * 4 + r][jl] = (uint16_t)((f2bf(hn) & 0xFFFEu) | tauw);
            }
        }
        __syncthreads();  // F: Als[1-p] own half complete (orders publish read)
        // ---- publish own 16B chunk via proven atomic stores; then
        //      early-issue next poll loads (compiler-managed waits) ----
        if (t + 1 < T_) {
            const u64t* sp = (const u64t*)&Als[1 - p][orow][ocol];
            u64t o0 = sp[0], o1 = sp[1];
            u64t* pp = (u64t*)(Hbuf + (size_t)(1 - p) * (B_ * H_) + ooff);
            __hip_atomic_store(&pp[0], o0, __ATOMIC_RELAXED,
                               __HIP_MEMORY_SCOPE_AGENT);
            __hip_atomic_store(&pp[1], o1, __ATOMIC_RELAXED,
                               __HIP_MEMORY_SCOPE_AGENT);
            const u64t* gn = (const u64t*)(Hbuf + (size_t)(1 - p) * (B_ * H_) + poff);
            e0 = __hip_atomic_load(&gn[0], __ATOMIC_RELAXED,
                                   __HIP_MEMORY_SCOPE_AGENT);
            e1 = __hip_atomic_load(&gn[1], __ATOMIC_RELAXED,
                                   __HIP_MEMORY_SCOPE_AGENT);
        }
        // ---- out stores — plain (retire in local L2), off the chain ----
        #pragma unroll
        for (int nt = 0; nt < 2; ++nt) {
            int jg = s * 256 + (2 * w + nt) * 16 + c;
            #pragma unroll
            for (int r = 0; r < 4; ++r) {
                int bg = g * 16 + q * 4 + r;
                out[((size_t)bg * T_ + t) * H_ + jg] = hold[nt][r];
            }
        }
    }
}

extern "C" void kernel_launch(void* const* d_in, const int* in_sizes, int n_in,
                              void* d_out, int out_size, void* d_ws, size_t ws_size,
                              hipStream_t stream) {
    const float* x     = (const float*)d_in[0];
    const float* W     = (const float*)d_in[1];
    const float* U     = (const float*)d_in[2];
    const float* bias  = (const float*)d_in[3];
    const float* alpha = (const float*)d_in[4];
    const float* beta  = (const float*)d_in[5];
    float* out = (float*)d_out;

    char* ws = (char*)d_ws;
    float* wxb = (float*)ws;                                  // 64 MiB
    uint16_t* Hbuf = (uint16_t*)(ws + WXB_BYTES);             // 128 KiB tagged bf16

    // Warm-up tag safety: parity 0 halves get LSB=0 (invalid at t'=2 which
    // expects tau=1), parity 1 halves get LSB=1 (invalid at t'=1, tau=0).
    hipMemsetAsync(Hbuf, 0x00, HHALF_BYTES, stream);
    hipMemsetAsync((char*)Hbuf + HHALF_BYTES, 0xFF, HHALF_BYTES, stream);

    wx_gemm<<<dim3((M_ / 64) * (H_ / 64)), dim3(256), 0, stream>>>(x, W, bias, wxb);
    rnn_scan<<<dim3(8), dim3(512), 0, stream>>>(U, wxb, alpha, beta, out, Hbuf);
}

// Round 8
// 1165.360 us; speedup vs baseline: 1.3988x; 1.3988x over previous
//
#include <hip/hip_runtime.h>
#include <stdint.h>

// FastRNN: B=64, T=512, I=256, H=512, fp32.
//   K1: wx = x @ W + bias  (bf16 MFMA GEMM) — unchanged.
//   K2: h_t = sb*h + sa*tanh(wx_t + h @ U).
// R14 = R13 with the t=0 staging zeroing FIXED. R13's failure (absmax
//   0.0945 = 2*sigmoid(-3) exactly, fast run = no protocol stall) was
//   uninitialized Als[0]: the zeroing covered only 1024 of 2048 u64s
//   (every 32-col segment's low half). wx_gemm's LDS leftovers flowed
//   through h_{-1}@U into h_0. Now 8 u64/thread = full 16x512 tile.
// R13 structure (kept): R9 base (16 blocks = 4 batch-groups x 4 j-slices,
//   256 thr) + split accumulation: own 128 cols of h_{t+1} land in LDS at
//   epilogue; after barrier F publish them, then compute acc_own =
//   h_own@U_own (4 ktiles) WHILE publishes propagate through the LLC;
//   step t+1 polls only 12KB (3 partner slices) and does 12 ktiles.
//   Exchange primitives: proven __hip_atomic_load/store relaxed-agent.

#define B_ 64
#define T_ 512
#define I_ 256
#define H_ 512
#define M_ (B_ * T_)  // 32768

#define WXB_BYTES  ((size_t)M_ * H_ * 4)       // 64 MiB fp32
#define HHALF_BYTES ((size_t)B_ * H_ * 2)      // 64 KiB bf16 per parity

typedef short v8s __attribute__((ext_vector_type(8)));
typedef float v4f __attribute__((ext_vector_type(4)));
typedef unsigned long long u64t;

__device__ __forceinline__ uint16_t f2bf(float x) {
    union { float f; uint32_t u; } v; v.f = x;
    return (uint16_t)((v.u + 0x7FFFu + ((v.u >> 16) & 1u)) >> 16);
}

// --------------- K1: wxb[m][j] = x[m][:] @ W[:][j] + bias[j] ----------------
__global__ __launch_bounds__(256) void wx_gemm(
        const float* __restrict__ x, const float* __restrict__ W,
        const float* __restrict__ bias, float* __restrict__ wxb) {
    __shared__ uint16_t Asl[64][40];
    __shared__ uint16_t Bsl[4 * 64 * 8];

    const int tid = threadIdx.x;
    const int lane = tid & 63;
    const int w = tid >> 6;
    const int q = lane >> 4, c = lane & 15;
    const int mbase = (int)(blockIdx.x >> 3) * 64;
    const int nbase = (int)(blockIdx.x & 7) * 64;

    v4f acc[4];
    #pragma unroll
    for (int i = 0; i < 4; ++i) acc[i] = (v4f){0.f, 0.f, 0.f, 0.f};

    for (int ks = 0; ks < I_; ks += 32) {
        {
            int row = tid >> 2, c4 = tid & 3;
            const float* gp = x + (size_t)(mbase + row) * I_ + ks + c4 * 8;
            float4 f0 = *(const float4*)gp;
            float4 f1 = *(const float4*)(gp + 4);
            uint16_t* dp = &Asl[row][c4 * 8];
            dp[0] = f2bf(f0.x); dp[1] = f2bf(f0.y); dp[2] = f2bf(f0.z); dp[3] = f2bf(f0.w);
            dp[4] = f2bf(f1.x); dp[5] = f2bf(f1.y); dp[6] = f2bf(f1.z); dp[7] = f2bf(f1.w);
        }
        {
            int nt = tid >> 6;
            const float* gp = W + (size_t)(ks + q * 8) * H_ + nbase + nt * 16 + c;
            union { v8s v; uint16_t u[8]; } pk;
            #pragma unroll
            for (int jj = 0; jj < 8; ++jj) pk.u[jj] = f2bf(gp[(size_t)jj * H_]);
            *(v8s*)&Bsl[(nt * 64 + lane) * 8] = pk.v;
        }
        __syncthreads();
        const v8s* Bf = (const v8s*)Bsl;
        v8s a = *(const v8s*)&Asl[w * 16 + c][q * 8];
        #pragma unroll
        for (int nt = 0; nt < 4; ++nt) {
            v8s b = Bf[nt * 64 + lane];
            acc[nt] = __builtin_amdgcn_mfma_f32_16x16x32_bf16(a, b, acc[nt], 0, 0, 0);
        }
        __syncthreads();
    }
    #pragma unroll
    for (int nt = 0; nt < 4; ++nt) {
        int j = nbase + nt * 16 + c;
        float bj = bias[j];
        #pragma unroll
        for (int r = 0; r < 4; ++r) {
            int m = mbase + w * 16 + q * 4 + r;
            wxb[(size_t)m * H_ + j] = acc[nt][r] + bj;
        }
    }
}

// --------------- K2: recurrent scan ----------------------------------------
__global__ __launch_bounds__(256, 1) void rnn_scan(
        const float* __restrict__ U, const float* __restrict__ wxb,
        const float* __restrict__ alpha, const float* __restrict__ beta,
        float* __restrict__ out, uint16_t* __restrict__ Hbuf) {
    __shared__ __align__(16) uint16_t Als[2][16][520];  // dbuf full-H state, +8 pad

    const int bid = blockIdx.x;       // 0..15
    const int g = bid >> 2, s = bid & 3;
    const int tid = threadIdx.x;      // 0..255
    const int lane = tid & 63;
    const int w = tid >> 6;           // wave 0..3
    const int q = lane >> 4, c = lane & 15;

    float sa, sb;
    { float a = alpha[0], b = beta[0];
      sa = 1.f / (1.f + __expf(-a)); sb = 1.f / (1.f + __expf(-b)); }

    // Loop-invariant U B-frags, stored [12 partner ktiles | 4 own ktiles]
    // so step loops use compile-time slot indices (rule-#20 safe).
    // slot<12 -> global ktile = slot + (slot >= 4s ? 4 : 0);
    // slot>=12 -> global ktile = 4s + (slot-12).
    v8s Uf[2][16];
    #pragma unroll
    for (int nt = 0; nt < 2; ++nt) {
        int jg = s * 128 + (2 * w + nt) * 16 + c;
        #pragma unroll
        for (int slot = 0; slot < 16; ++slot) {
            int ktile = (slot < 12) ? (slot + ((slot >= (s << 2)) ? 4 : 0))
                                    : ((s << 2) + slot - 12);
            const float* gp = U + (size_t)(ktile * 32 + q * 8) * H_ + jg;
            union { v8s v; uint16_t u[8]; } pk;
            #pragma unroll
            for (int jj = 0; jj < 8; ++jj) pk.u[jj] = f2bf(gp[(size_t)jj * H_]);
            Uf[nt][slot] = pk.v;
        }
    }
    float hold[2][4];
    #pragma unroll
    for (int nt = 0; nt < 2; ++nt)
        #pragma unroll
        for (int r = 0; r < 4; ++r) hold[nt][r] = 0.f;

    // wx prefetch: one step ahead.
    float wxv[2][4], wxn[2][4];
    #pragma unroll
    for (int nt = 0; nt < 2; ++nt) {
        int jg = s * 128 + (2 * w + nt) * 16 + c;
        #pragma unroll
        for (int r = 0; r < 4; ++r) {
            int bg = g * 16 + q * 4 + r;
            wxn[nt][r] = __builtin_nontemporal_load(
                &wxb[((size_t)bg * T_ + 0) * H_ + jg]);
        }
    }

    // Partner poll mapping: 3 partner slices s'(i) = i + (i>=s), each thread
    // owns one 16B chunk per slice: row tid>>4, cols s'*128 + (tid&15)*8.
    // 16 consecutive threads read 256B contiguous.
    const int prow = tid >> 4;
    size_t poffv[3];
    int pcolv[3];
    #pragma unroll
    for (int i = 0; i < 3; ++i) {
        int sp = i + ((i >= s) ? 1 : 0);
        pcolv[i] = sp * 128 + (tid & 15) * 8;
        poffv[i] = ((size_t)(g * 16 + prow)) * H_ + pcolv[i];
    }
    // Publish mapping: own chunk row tid>>4, cols s*128 + (tid&15)*8.
    const int orow = tid >> 4;
    const int ocol = s * 128 + (tid & 15) * 8;
    const size_t ooff = ((size_t)(g * 16 + orow)) * H_ + ocol;

    // Zero ALL of Als[0] (h_0 = 0): 16 rows x 512 u16 = 2048 u64s;
    // 256 threads x 8 u64 each. (R13 bug: only half was zeroed.)
    #pragma unroll
    for (int u = 0; u < 8; ++u)
        *((u64t*)&Als[0][tid >> 4][0] + (tid & 15) * 8 + u) = 0;

    u64t ev[3][2];                 // early-issued partner poll loads
    v4f accO0 = (v4f){0.f, 0.f, 0.f, 0.f};   // own-ktile contribution
    v4f accO1 = (v4f){0.f, 0.f, 0.f, 0.f};   // (h_0 = 0 -> zero)

    for (int t = 0; t < T_; ++t) {
        const int p = t & 1;
        // rotate wx prefetch buffer
        #pragma unroll
        for (int nt = 0; nt < 2; ++nt)
            #pragma unroll
            for (int r = 0; r < 4; ++r) wxv[nt][r] = wxn[nt][r];

        // ---- poll 3 partner slices into Als[p] (own slice was written by
        //      last step's epilogue); R6-proven atomic check-reload loop ----
        if (t > 0) {
            const uint16_t* hbp = Hbuf + (size_t)p * (B_ * H_);
            const u64t lsb = 0x0001000100010001ull;
            const u64t want = ((t >> 1) & 1) ? lsb : 0ull;
            for (int guard = 0; guard < (1 << 20); ++guard) {
                u64t x = (ev[0][0] ^ want) | (ev[0][1] ^ want)
                       | (ev[1][0] ^ want) | (ev[1][1] ^ want)
                       | (ev[2][0] ^ want) | (ev[2][1] ^ want);
                if (!(x & lsb)) break;
                #pragma unroll
                for (int i = 0; i < 3; ++i) {
                    const u64t* gp = (const u64t*)(hbp + poffv[i]);
                    ev[i][0] = __hip_atomic_load(&gp[0], __ATOMIC_RELAXED,
                                                 __HIP_MEMORY_SCOPE_AGENT);
                    ev[i][1] = __hip_atomic_load(&gp[1], __ATOMIC_RELAXED,
                                                 __HIP_MEMORY_SCOPE_AGENT);
                }
            }
            #pragma unroll
            for (int i = 0; i < 3; ++i) {
                u64t* dp = (u64t*)&Als[p][prow][pcolv[i]];
                dp[0] = ev[i][0]; dp[1] = ev[i][1];
            }
        }
        __syncthreads();  // C: Als[p] complete
        // ---- partner-ktile MFMA (12 ktiles); own 4 were done last tail ----
        v4f acc0 = accO0;
        v4f acc1 = accO1;
        #pragma unroll
        for (int i = 0; i < 12; ++i) {
            int ktp = i + ((i >= (s << 2)) ? 4 : 0);
            v8s a = *(const v8s*)((const uint16_t*)&Als[p][c][0] + ktp * 32 + q * 8);
            acc0 = __builtin_amdgcn_mfma_f32_16x16x32_bf16(a, Uf[0][i], acc0, 0, 0, 0);
            acc1 = __builtin_amdgcn_mfma_f32_16x16x32_bf16(a, Uf[1][i], acc1, 0, 0, 0);
        }
        // ---- epilogue: fp32 state in regs; tagged bf16 -> Als[1-p] own
        //      region (this IS next step's A-staging for our slice) ----
        const uint16_t tauw = (uint16_t)(((t + 1) >> 1) & 1);
        #pragma unroll
        for (int nt = 0; nt < 2; ++nt) {
            v4f av = nt ? acc1 : acc0;
            int jl = s * 128 + (2 * w + nt) * 16 + c;
            #pragma unroll
            for (int r = 0; r < 4; ++r) {
                float pre = av[r] + wxv[nt][r];
                float ex = __expf(pre + pre);                           // e^{2x}
                float ct = 1.f - 2.f * __builtin_amdgcn_rcpf(ex + 1.f); // tanh
                float hn = sb * hold[nt][r] + sa * ct;
                hold[nt][r] = hn;
                Als[1 - p][q * 4 + r][jl] = (uint16_t)((f2bf(hn) & 0xFFFEu) | tauw);
            }
        }
        __syncthreads();  // F: Als[1-p] own region complete
        if (t + 1 < T_) {
            // ---- publish own chunk FIRST (partner's critical path) ----
            {
                const u64t* sp = (const u64t*)&Als[1 - p][orow][ocol];
                u64t o0 = sp[0], o1 = sp[1];
                u64t* pp = (u64t*)(Hbuf + (size_t)(1 - p) * (B_ * H_) + ooff);
                __hip_atomic_store(&pp[0], o0, __ATOMIC_RELAXED,
                                   __HIP_MEMORY_SCOPE_AGENT);
                __hip_atomic_store(&pp[1], o1, __ATOMIC_RELAXED,
                                   __HIP_MEMORY_SCOPE_AGENT);
            }
            // ---- own-ktile MFMA for t+1 — overlaps the LLC propagation ----
            accO0 = (v4f){0.f, 0.f, 0.f, 0.f};
            accO1 = (v4f){0.f, 0.f, 0.f, 0.f};
            #pragma unroll
            for (int i = 0; i < 4; ++i) {
                int kto = (s << 2) + i;
                v8s a = *(const v8s*)((const uint16_t*)&Als[1 - p][c][0] + kto * 32 + q * 8);
                accO0 = __builtin_amdgcn_mfma_f32_16x16x32_bf16(a, Uf[0][12 + i], accO0, 0, 0, 0);
                accO1 = __builtin_amdgcn_mfma_f32_16x16x32_bf16(a, Uf[1][12 + i], accO1, 0, 0, 0);
            }
            // ---- wx prefetch for t+1 (off the critical chain) ----
            #pragma unroll
            for (int nt = 0; nt < 2; ++nt) {
                int jg = s * 128 + (2 * w + nt) * 16 + c;
                #pragma unroll
                for (int r = 0; r < 4; ++r) {
                    int bg = g * 16 + q * 4 + r;
                    wxn[nt][r] = __builtin_nontemporal_load(
                        &wxb[((size_t)bg * T_ + (t + 1)) * H_ + jg]);
                }
            }
            // ---- early-issue next poll loads (compiler-managed waits;
            //      stale data caught by the tag check) ----
            const uint16_t* hbn = Hbuf + (size_t)(1 - p) * (B_ * H_);
            #pragma unroll
            for (int i = 0; i < 3; ++i) {
                const u64t* gp = (const u64t*)(hbn + poffv[i]);
                ev[i][0] = __hip_atomic_load(&gp[0], __ATOMIC_RELAXED,
                                             __HIP_MEMORY_SCOPE_AGENT);
                ev[i][1] = __hip_atomic_load(&gp[1], __ATOMIC_RELAXED,
                                             __HIP_MEMORY_SCOPE_AGENT);
            }
        }
        // ---- out stores — plain (retire in local L2), off the chain ----
        #pragma unroll
        for (int nt = 0; nt < 2; ++nt) {
            int jg = s * 128 + (2 * w + nt) * 16 + c;
            #pragma unroll
            for (int r = 0; r < 4; ++r) {
                int bg = g * 16 + q * 4 + r;
                out[((size_t)bg * T_ + t) * H_ + jg] = hold[nt][r];
            }
        }
    }
}

extern "C" void kernel_launch(void* const* d_in, const int* in_sizes, int n_in,
                              void* d_out, int out_size, void* d_ws, size_t ws_size,
                              hipStream_t stream) {
    const float* x     = (const float*)d_in[0];
    const float* W     = (const float*)d_in[1];
    const float* U     = (const float*)d_in[2];
    const float* bias  = (const float*)d_in[3];
    const float* alpha = (const float*)d_in[4];
    const float* beta  = (const float*)d_in[5];
    float* out = (float*)d_out;

    char* ws = (char*)d_ws;
    float* wxb = (float*)ws;                                  // 64 MiB
    uint16_t* Hbuf = (uint16_t*)(ws + WXB_BYTES);             // 128 KiB tagged bf16

    // Warm-up tag safety: parity 0 halves get LSB=0 (invalid at t'=2 which
    // expects tau=1), parity 1 halves get LSB=1 (invalid at t'=1, tau=0).
    hipMemsetAsync(Hbuf, 0x00, HHALF_BYTES, stream);
    hipMemsetAsync((char*)Hbuf + HHALF_BYTES, 0xFF, HHALF_BYTES, stream);

    wx_gemm<<<dim3((M_ / 64) * (H_ / 64)), dim3(256), 0, stream>>>(x, W, bias, wxb);
    rnn_scan<<<dim3(16), dim3(256), 0, stream>>>(U, wxb, alpha, beta, out, Hbuf);
}